// Round 25
// baseline (195.407 us; speedup 1.0000x reference)
//
#include <hip/hip_runtime.h>
#include <hip/hip_bf16.h>
#include <math.h>

// Dims (compile-time constants for this problem)
#define Bb 2
#define Tt 1024
#define Dd 512
#define Hh 8
#define Kk 64
#define Vv 64
#define BT (Bb*Tt)          // 2048
#define HK (Hh*Kk)          // 512

// hyperparams
#define B1c 0.9f
#define B2c 0.999f
#define LRc 1e-3f
#define SCALEc 0.125f       // 64^-0.5

typedef short s8v __attribute__((ext_vector_type(8)));   // 8 bf16 = 4 VGPR
typedef float f4v __attribute__((ext_vector_type(4)));   // MFMA acc

// ---------------------------------------------------------------------------
// bf16 split helpers (RNE)
// ---------------------------------------------------------------------------
__device__ __forceinline__ unsigned short f2bf(float x) {
  unsigned u = __float_as_uint(x);
  u += 0x7FFFu + ((u >> 16) & 1u);
  return (unsigned short)(u >> 16);
}
__device__ __forceinline__ float bf2f(unsigned short h) {
  return __uint_as_float((unsigned)h << 16);
}

// ---------------------------------------------------------------------------
// Cross-lane helpers: all-VALU butterfly stages
// ---------------------------------------------------------------------------
template <int CTRL>
__device__ __forceinline__ float dpp_add(float v) {
  int y = __builtin_amdgcn_update_dpp(0, __float_as_int(v), CTRL, 0xF, 0xF, true);
  return v + __int_as_float(y);
}

typedef unsigned uint2_t __attribute__((ext_vector_type(2)));

__device__ __forceinline__ float xor16_add(float x) {
#if __has_builtin(__builtin_amdgcn_permlane16_swap)
  uint2_t r = __builtin_amdgcn_permlane16_swap(__float_as_uint(x), __float_as_uint(x),
                                               false, false);
  return __uint_as_float(r.x) + __uint_as_float(r.y);
#else
  int y = __builtin_amdgcn_ds_swizzle(__float_as_int(x), 0x401F);
  return x + __int_as_float(y);
#endif
}

__device__ __forceinline__ float xor32_add(float x) {
#if __has_builtin(__builtin_amdgcn_permlane32_swap)
  uint2_t r = __builtin_amdgcn_permlane32_swap(__float_as_uint(x), __float_as_uint(x),
                                               false, false);
  return __uint_as_float(r.x) + __uint_as_float(r.y);
#else
  return x + __shfl_xor(x, 32, 64);
#endif
}

__device__ __forceinline__ float reduce16(float x) {
  x = dpp_add<0xB1>(x);
  x = dpp_add<0x4E>(x);
  x = dpp_add<0x141>(x);
  x = dpp_add<0x140>(x);
  return x;
}

__device__ __forceinline__ float reduce64(float x) {
  x = reduce16(x);
  x = xor16_add(x);
  x = xor32_add(x);
  return x;
}

// ---------------------------------------------------------------------------
// cvt_x: fp32 [M][512] -> hi/lo bf16 [M][512] (row-major)
// ---------------------------------------------------------------------------
__global__ __launch_bounds__(256) void cvt_x_kernel(
    const float* __restrict__ x, unsigned short* __restrict__ hi,
    unsigned short* __restrict__ lo) {
  const int i = (blockIdx.x * 256 + threadIdx.x) * 8;
  float4 a = *(const float4*)(x + i);
  float4 b = *(const float4*)(x + i + 4);
  const float v[8] = {a.x, a.y, a.z, a.w, b.x, b.y, b.z, b.w};
  union { unsigned short u[8]; uint4 q; } ph, pl;
#pragma unroll
  for (int j = 0; j < 8; ++j) {
    unsigned short h = f2bf(v[j]);
    ph.u[j] = h;
    pl.u[j] = f2bf(v[j] - bf2f(h));
  }
  *(uint4*)(hi + i) = ph.q;
  *(uint4*)(lo + i) = pl.q;
}

// ---------------------------------------------------------------------------
// cvt_w: W [512 k][512 n] fp32 -> hi/lo bf16 TRANSPOSED [n][k].
// ---------------------------------------------------------------------------
__global__ __launch_bounds__(256) void cvt_w_kernel(
    const float* __restrict__ W0, const float* __restrict__ W1,
    const float* __restrict__ W2,
    unsigned short* __restrict__ hib, unsigned short* __restrict__ lob) {
  __shared__ float Ts[64][65];
  const int z = blockIdx.z;
  const float* W = (z == 0) ? W0 : (z == 1) ? W1 : W2;
  unsigned short* hi = hib + (size_t)z * 512 * 512;
  unsigned short* lo = lob + (size_t)z * 512 * 512;
  const int tk = blockIdx.x * 64;
  const int tn = blockIdx.y * 64;
  const int r  = threadIdx.x >> 2;
  const int cg = threadIdx.x & 3;
#pragma unroll
  for (int j = 0; j < 4; ++j) {
    float4 v = *(const float4*)(W + (size_t)(tk + r) * 512 + tn + cg * 16 + j * 4);
    Ts[r][cg * 16 + j * 4 + 0] = v.x;
    Ts[r][cg * 16 + j * 4 + 1] = v.y;
    Ts[r][cg * 16 + j * 4 + 2] = v.z;
    Ts[r][cg * 16 + j * 4 + 3] = v.w;
  }
  __syncthreads();
  union { unsigned short u[16]; uint4 q[2]; } ph, pl;
#pragma unroll
  for (int j = 0; j < 16; ++j) {
    float v = Ts[cg * 16 + j][r];
    unsigned short h = f2bf(v);
    ph.u[j] = h;
    pl.u[j] = f2bf(v - bf2f(h));
  }
  const size_t ob = (size_t)(tn + r) * 512 + tk + cg * 16;
  *(uint4*)(hi + ob) = ph.q[0];
  *(uint4*)(hi + ob + 8) = ph.q[1];
  *(uint4*)(lo + ob) = pl.q[0];
  *(uint4*)(lo + ob + 8) = pl.q[1];
}

// ---------------------------------------------------------------------------
// split-bf16 MFMA GEMM — 64x64 tile (R16/R20 winner)
// ---------------------------------------------------------------------------
__device__ __forceinline__ void gemm_mfma_body(
    const unsigned short* __restrict__ Ahi, const unsigned short* __restrict__ Alo,
    const unsigned short* __restrict__ Bhi, const unsigned short* __restrict__ Blo,
    float* __restrict__ C) {
  __shared__ unsigned short Ah[64][40], Al[64][40], Bh[64][40], Bl[64][40];
  const int tid = threadIdx.x;
  const int bm = blockIdx.x * 64;
  const int bn = blockIdx.y * 64;
  const int srow = tid >> 2;
  const int skoff = (tid & 3) * 8;
  const int l = tid & 63, w = tid >> 6;
  const int arow = (l & 15) + 16 * w;
  const int koff = (l >> 4) * 8;

  const unsigned short* pAh = Ahi + (size_t)(bm + srow) * 512 + skoff;
  const unsigned short* pAl = Alo + (size_t)(bm + srow) * 512 + skoff;
  const unsigned short* pBh = Bhi + (size_t)(bn + srow) * 512 + skoff;
  const unsigned short* pBl = Blo + (size_t)(bn + srow) * 512 + skoff;

  f4v acc0 = {0.f, 0.f, 0.f, 0.f}, acc1 = acc0, acc2 = acc0, acc3 = acc0;

  uint4 rah = *(const uint4*)(pAh);
  uint4 ral = *(const uint4*)(pAl);
  uint4 rbh = *(const uint4*)(pBh);
  uint4 rbl = *(const uint4*)(pBl);

  for (int k0 = 0; k0 < 512; k0 += 32) {
    __syncthreads();
    *(uint4*)&Ah[srow][skoff] = rah;
    *(uint4*)&Al[srow][skoff] = ral;
    *(uint4*)&Bh[srow][skoff] = rbh;
    *(uint4*)&Bl[srow][skoff] = rbl;
    __syncthreads();
    if (k0 + 32 < 512) {
      rah = *(const uint4*)(pAh + k0 + 32);
      ral = *(const uint4*)(pAl + k0 + 32);
      rbh = *(const uint4*)(pBh + k0 + 32);
      rbl = *(const uint4*)(pBl + k0 + 32);
    }
    const s8v ah = *(const s8v*)&Ah[arow][koff];
    const s8v al = *(const s8v*)&Al[arow][koff];
#pragma unroll
    for (int c = 0; c < 4; ++c) {
      const s8v bh = *(const s8v*)&Bh[16 * c + (l & 15)][koff];
      const s8v bl = *(const s8v*)&Bl[16 * c + (l & 15)][koff];
      f4v* acc = (c == 0) ? &acc0 : (c == 1) ? &acc1 : (c == 2) ? &acc2 : &acc3;
      *acc = __builtin_amdgcn_mfma_f32_16x16x32_bf16(al, bh, *acc, 0, 0, 0);
      *acc = __builtin_amdgcn_mfma_f32_16x16x32_bf16(ah, bl, *acc, 0, 0, 0);
      *acc = __builtin_amdgcn_mfma_f32_16x16x32_bf16(ah, bh, *acc, 0, 0, 0);
    }
  }

  const int crow = bm + 16 * w + (l >> 4) * 4;
  const int ccol = bn + (l & 15);
#pragma unroll
  for (int i = 0; i < 4; ++i) {
    C[(size_t)(crow + i) * 512 + ccol + 0]  = acc0[i];
    C[(size_t)(crow + i) * 512 + ccol + 16] = acc1[i];
    C[(size_t)(crow + i) * 512 + ccol + 32] = acc2[i];
    C[(size_t)(crow + i) * 512 + ccol + 48] = acc3[i];
  }
}

__global__ __launch_bounds__(256) void gemm3_mfma_kernel(
    const unsigned short* __restrict__ xhi, const unsigned short* __restrict__ xlo,
    const unsigned short* __restrict__ whi, const unsigned short* __restrict__ wlo,
    float* __restrict__ qp, float* __restrict__ kp, float* __restrict__ vp) {
  const int z = blockIdx.z;
  float* Cp = (z == 0) ? qp : (z == 1) ? kp : vp;
  gemm_mfma_body(xhi, xlo, whi + (size_t)z * 512 * 512, wlo + (size_t)z * 512 * 512, Cp);
}

__global__ __launch_bounds__(256) void gemm1_mfma_kernel(
    const unsigned short* __restrict__ ahi, const unsigned short* __restrict__ alo,
    const unsigned short* __restrict__ whi, const unsigned short* __restrict__ wlo,
    float* __restrict__ C) {
  gemm_mfma_body(ahi, alo, whi, wlo, C);
}

// ---------------------------------------------------------------------------
// beta = sigmoid(x @ Wb) (float4-vectorized)
// ---------------------------------------------------------------------------
__global__ __launch_bounds__(256) void beta_kernel(const float* __restrict__ x,
                                                   const float* __restrict__ Wb,
                                                   float* __restrict__ beta) {
  int gid = blockIdx.x * blockDim.x + threadIdx.x;
  int bt = gid >> 3, h = gid & 7;
  const float4* xr = (const float4*)(x + (size_t)bt * Dd);
  float s = 0.f;
#pragma unroll 4
  for (int d4 = 0; d4 < Dd / 4; ++d4) {
    float4 xv = xr[d4];
    const float* wb = Wb + (d4 * 4) * Hh + h;
    s = fmaf(xv.x, wb[0 * Hh], s);
    s = fmaf(xv.y, wb[1 * Hh], s);
    s = fmaf(xv.z, wb[2 * Hh], s);
    s = fmaf(xv.w, wb[3 * Hh], s);
  }
  beta[gid] = 1.f / (1.f + expf(-s));
}

// ---------------------------------------------------------------------------
// causal depthwise conv(4) + SiLU (+ optional L2 norm + scale)
// ---------------------------------------------------------------------------
__global__ __launch_bounds__(256) void conv_kernel(
    const float* __restrict__ qp, const float* __restrict__ kp,
    const float* __restrict__ vp,
    const float* __restrict__ cwq, const float* __restrict__ cwk,
    const float* __restrict__ cwv,
    float* __restrict__ qc, float* __restrict__ kc, float* __restrict__ vc) {
  const int mode = blockIdx.z;
  const float* pre; const float* cw; float* post;
  if (mode == 0)      { pre = qp; cw = cwq; post = qc; }
  else if (mode == 1) { pre = kp; cw = cwk; post = kc; }
  else                { pre = vp; cw = cwv; post = vc; }

  const int idx = blockIdx.x * 4 + (threadIdx.x >> 6);
  const int lane = threadIdx.x & 63;
  const int b = idx >> 13;
  const int th = idx & 8191;
  const int t = th >> 3;
  const int h = th & 7;
  const int ch = h * 64 + lane;

  float y = 0.f;
#pragma unroll
  for (int i = 0; i < 4; ++i) {
    int tt = t + i - 3;
    if (tt >= 0)
      y += pre[((size_t)(b * Tt + tt)) * HK + ch] * cw[ch * 4 + i];
  }
  y = y / (1.f + expf(-y));
  if (mode < 2) {
    float ss = reduce64(y * y);
    y *= rsqrtf(ss + 1e-6f);
    if (mode == 0) y *= SCALEc;
  }
  post[((size_t)(b * Tt + t)) * HK + ch] = y;
}

// ---------------------------------------------------------------------------
// sequential IVON delta-rule scan — producer/consumer, reduce16 producer.
//
// R24 (253cy/step A-wall): chain = head ~30 + reduce64 ~115. This round the
// producer uses the R12 geometry stripped to S-chain only: ONE A-wave (wave
// 0) handles all 4 columns — 16 lanes/col, 4 k/lane, all-DPP reduce16 (4
// stages, ~76cy). Chain ~= 28 head + 12 tree + 76 = ~116cy. A's ~50-instr
// issue hides under B. Block = 320 thr: wave 0 = A, waves 1-4 = B
// (staging + o-consumer for the previous tile, unchanged logic, cb=wave-1).
// S handoff: A writes float4 S per (col, k-group) into Sb in the k-indexed
// layout B already reads. Triple-buffered ks/qs/vb; double-buffered Sb;
// single barrier per tile.
// ---------------------------------------------------------------------------
#define TC 32           // steps per LDS tile
#define NT (Tt / TC)    // 32 tiles

__global__ __launch_bounds__(320) void scan_kernel(
    const float* __restrict__ qc, const float* __restrict__ kc,
    const float* __restrict__ vc, const float* __restrict__ beta,
    float* __restrict__ o) {
  __shared__ float  ks[3][TC][64];     // 24576 B
  __shared__ float  qs[3][TC][64];     // 24576 B
  __shared__ float2 vb[3][TC][4];      //  3072 B
  __shared__ float  Sb[2][TC][4][64];  // 65536 B

  const int tid  = threadIdx.x;       // 0..319
  const int lane = tid & 63;
  const int wave = tid >> 6;          // 0..4
  const int bid  = blockIdx.x;        // 0..255
  const int vq   = bid >> 4;          // 0..15 (column quad)
  const int bh   = bid & 15;          // bid%8 == bh%8 -> XCD affinity
  const int b = bh >> 3, h = bh & 7;

  const size_t base2 = ((size_t)b * Tt) * HK + h * 64;
  const float* bp = beta + ((size_t)b * Tt) * Hh + h;

  // A-wave lane mapping: 16 lanes per column, 4 k per lane
  const int g    = lane & 15;         // k-group: k = 4g..4g+3
  const int cgrp = lane >> 4;         // column 0..3

  // B staging thread mapping (tid2 = tid-64, 0..255 for waves 1..4)
  const int tid2 = tid - 64;
  const int sr = (tid2 & 255) >> 4;   // 0..15 (also +16)
  const int sg = tid2 & 15;
  const int vr = (tid2 & 255) >> 3;   // 0..31
  const int vcc = tid2 & 3;

  // ---- prologue: B stages tile 0 into buffer 0 ----
  if (wave >= 1) {
    float4 k0 = *(const float4*)(kc + base2 + (size_t)sr * HK + sg * 4);
    float4 q0 = *(const float4*)(qc + base2 + (size_t)sr * HK + sg * 4);
    float4 k1 = *(const float4*)(kc + base2 + (size_t)(sr + 16) * HK + sg * 4);
    float4 q1 = *(const float4*)(qc + base2 + (size_t)(sr + 16) * HK + sg * 4);
    *(float4*)&ks[0][sr][sg * 4] = k0;
    *(float4*)&qs[0][sr][sg * 4] = q0;
    *(float4*)&ks[0][sr + 16][sg * 4] = k1;
    *(float4*)&qs[0][sr + 16][sg * 4] = q1;
    if ((tid2 & 7) < 4) {
      float vv = vc[base2 + (size_t)vr * HK + vq * 4 + vcc];
      float lb = (0.1f * LRc) * bp[(size_t)vr * Hh];
      vb[0][vr][vcc] = make_float2(vv, lb);
    }
  }
  __syncthreads();

  // A state: 4 k-elements per lane (column cgrp)
  float S0 = 0, S1 = 0, S2 = 0, S3 = 0;
  float G0 = 0, G1 = 0, G2 = 0, G3 = 0;
  float H0 = 0, H1 = 0, H2 = 0, H3 = 0;
  float r0 = 1.f, r1 = 1.f, r2 = 1.f, r3 = 1.f;

  int d = 0;                           // tile % 3
  for (int tile = 0; tile < NT; ++tile) {
    const int dn = (d + 1 == 3) ? 0 : d + 1;   // (tile+1)%3
    const int dm = (d == 0) ? 2 : d - 1;       // (tile-1)%3
    const int sb = tile & 1, sbp = sb ^ 1;
    const int t0 = tile * TC;
    const int more = (tile + 1 < NT);

    if (wave == 0) {
      // ================= A: S-chain producer (4 cols) =================
      // tile-top pred (tile 0: S=0 -> pred 0)
      float4 kt = *(const float4*)&ks[d][0][g * 4];
      float pred = reduce16(fmaf(kt.x, S0, kt.y * S1) +
                            fmaf(kt.z, S2, kt.w * S3));
#pragma unroll
      for (int s = 0; s < TC; ++s) {
        const float4 kv = *(const float4*)&ks[d][s][g * 4];
        const float2 vbc = vb[d][s][cgrp];
        const float diff = pred - vbc.x;
        const float lrb = vbc.y;
        const float gr0 = kv.x * diff;
        const float gr1 = kv.y * diff;
        const float gr2 = kv.z * diff;
        const float gr3 = kv.w * diff;
        G0 = fmaf(B1c, G0, gr0);
        G1 = fmaf(B1c, G1, gr1);
        G2 = fmaf(B1c, G2, gr2);
        G3 = fmaf(B1c, G3, gr3);
        H0 = fmaf(B2c, H0, gr0 * gr0);
        H1 = fmaf(B2c, H1, gr1 * gr1);
        H2 = fmaf(B2c, H2, gr2 * gr2);
        H3 = fmaf(B2c, H3, gr3 * gr3);
        const float d0 = fmaf(H0, 0.001f, 1.0f);
        const float d1 = fmaf(H1, 0.001f, 1.0f);
        const float d2 = fmaf(H2, 0.001f, 1.0f);
        const float d3 = fmaf(H3, 0.001f, 1.0f);
        r0 = r0 * fmaf(-d0, r0, 2.0f);
        r1 = r1 * fmaf(-d1, r1, 2.0f);
        r2 = r2 * fmaf(-d2, r2, 2.0f);
        r3 = r3 * fmaf(-d3, r3, 2.0f);
        S0 = fmaf(-lrb, G0 * r0, S0);
        S1 = fmaf(-lrb, G1 * r1, S1);
        S2 = fmaf(-lrb, G2 * r2, S2);
        S3 = fmaf(-lrb, G3 * r3, S3);
        // hand off to consumer (k-indexed layout B reads)
        *(float4*)&Sb[sb][s][cgrp][g * 4] = make_float4(S0, S1, S2, S3);
        if (s + 1 < TC) {
          const float4 k1 = *(const float4*)&ks[d][s + 1][g * 4];
          pred = reduce16(fmaf(k1.x, S0, k1.y * S1) +
                          fmaf(k1.z, S2, k1.w * S3));
        }
      }
    } else {
      // ================= B: staging + o-consumer =================
      float4 nk0, nq0, nk1, nq1; float nv = 0.f, nb = 0.f;
      if (more) {
        const int tn = t0 + TC;
        nk0 = *(const float4*)(kc + base2 + (size_t)(tn + sr) * HK + sg * 4);
        nq0 = *(const float4*)(qc + base2 + (size_t)(tn + sr) * HK + sg * 4);
        nk1 = *(const float4*)(kc + base2 + (size_t)(tn + sr + 16) * HK + sg * 4);
        nq1 = *(const float4*)(qc + base2 + (size_t)(tn + sr + 16) * HK + sg * 4);
        if ((tid2 & 7) < 4) {
          nv = vc[base2 + (size_t)(tn + vr) * HK + vq * 4 + vcc];
          nb = (0.1f * LRc) * bp[(size_t)(tn + vr) * Hh];
        }
      }
      // compute o for the PREVIOUS tile (S in Sb[sbp], q in qs[dm])
      if (tile > 0) {
        const int cb = wave - 1;             // column within block
        float* opc = o + base2 + vq * 4 + cb;
        const int tp0 = t0 - TC;
#pragma unroll
        for (int s = 0; s < TC; ++s) {
          const float qv = qs[dm][s][lane];
          const float Sv = Sb[sbp][s][cb][lane];
          const float po = reduce64(qv * Sv);
          opc[(size_t)(tp0 + s) * HK] = po;  // maskless: uniform across wave
        }
      }
      // write staged tile t+1 into buffer dn
      if (more) {
        *(float4*)&ks[dn][sr][sg * 4] = nk0;
        *(float4*)&qs[dn][sr][sg * 4] = nq0;
        *(float4*)&ks[dn][sr + 16][sg * 4] = nk1;
        *(float4*)&qs[dn][sr + 16][sg * 4] = nq1;
        if ((tid2 & 7) < 4) vb[dn][vr][vcc] = make_float2(nv, nb);
      }
    }
    __syncthreads();
    d = dn;
  }

  // ---- epilogue: B computes o for the last tile ----
  if (wave >= 1) {
    const int dlast = (NT - 1) % 3;
    const int sbl = (NT - 1) & 1;
    const int cb = wave - 1;
    float* opc = o + base2 + vq * 4 + cb;
    const int tp0 = (NT - 1) * TC;
#pragma unroll
    for (int s = 0; s < TC; ++s) {
      const float qv = qs[dlast][s][lane];
      const float Sv = Sb[sbl][s][cb][lane];
      const float po = reduce64(qv * Sv);
      opc[(size_t)(tp0 + s) * HK] = po;
    }
  }
}

// ---------------------------------------------------------------------------
// RMSNorm over V=64, writes bf16 hi/lo for the MFMA output projection
// ---------------------------------------------------------------------------
__global__ __launch_bounds__(256) void rmsnorm_kernel(
    const float* __restrict__ o, const float* __restrict__ rmsw,
    unsigned short* __restrict__ hi, unsigned short* __restrict__ lo) {
  const int idx = blockIdx.x * 4 + (threadIdx.x >> 6);
  const int lane = threadIdx.x & 63;
  const float* p = o + (size_t)idx * 64;
  float y = p[lane];
  float ss = reduce64(y * y);
  y = y * rsqrtf(ss * (1.f / 64.f) + 1e-5f) * rmsw[lane];
  unsigned short h = f2bf(y);
  hi[(size_t)idx * 64 + lane] = h;
  lo[(size_t)idx * 64 + lane] = f2bf(y - bf2f(h));
}

// ---------------------------------------------------------------------------
extern "C" void kernel_launch(void* const* d_in, const int* in_sizes, int n_in,
                              void* d_out, int out_size, void* d_ws, size_t ws_size,
                              hipStream_t stream) {
  const float* x    = (const float*)d_in[0];
  const float* Wq   = (const float*)d_in[1];
  const float* Wk   = (const float*)d_in[2];
  const float* Wv   = (const float*)d_in[3];
  const float* Wb   = (const float*)d_in[4];
  const float* cwq  = (const float*)d_in[5];
  const float* cwk  = (const float*)d_in[6];
  const float* cwv  = (const float*)d_in[7];
  const float* rmsw = (const float*)d_in[8];
  const float* Wo   = (const float*)d_in[9];
  float* out = (float*)d_out;
  float* ws  = (float*)d_ws;

  const size_t SZ = (size_t)BT * HK;   // 1,048,576 floats
  float* qp   = ws;            // pre-conv q / scan output `on`
  float* kp   = ws + 1 * SZ;   // pre-conv k; dead after conv -> onhi
  float* vp   = ws + 2 * SZ;   // pre-conv v; dead after conv -> onlo
  float* qc   = ws + 3 * SZ;   // conv q; hosts xhi/xlo BEFORE conv
  float* kc   = ws + 4 * SZ;   // conv k; hosts Wqkv hi/lo BEFORE conv
  float* vc   = ws + 5 * SZ;   // conv v; hosts Wo hi/lo AFTER scan
  float* beta = ws + 6 * SZ;   // 16384 floats
  float* on   = qp;

  unsigned short* xhi  = (unsigned short*)qc;
  unsigned short* xlo  = xhi + SZ;
  unsigned short* wh3  = (unsigned short*)kc;
  unsigned short* wl3  = wh3 + 3 * 512 * 512;
  unsigned short* wohi = (unsigned short*)vc;
  unsigned short* wolo = wohi + 512 * 512;
  unsigned short* onhi = (unsigned short*)kp;
  unsigned short* onlo = (unsigned short*)vp;

  // 1. convert x and Wq/Wk/Wv to split-bf16 (W transposed to [n][k])
  cvt_x_kernel<<<dim3(BT * Dd / (256 * 8)), 256, 0, stream>>>(x, xhi, xlo);
  cvt_w_kernel<<<dim3(8, 8, 3), 256, 0, stream>>>(Wq, Wk, Wv, wh3, wl3);
  // 2. projections via MFMA (64x64 tiles)
  gemm3_mfma_kernel<<<dim3(BT / 64, HK / 64, 3), 256, 0, stream>>>(
      xhi, xlo, wh3, wl3, qp, kp, vp);
  // 3. beta
  beta_kernel<<<dim3(BT * Hh / 256), 256, 0, stream>>>(x, Wb, beta);
  // 4. conv + silu + l2norm
  conv_kernel<<<dim3(Bb * Tt * Hh / 4, 1, 3), 256, 0, stream>>>(
      qp, kp, vp, cwq, cwk, cwv, qc, kc, vc);
  // 5. sequential scan: 256 blocks x 5 waves (1 producer + 4 consumer)
  scan_kernel<<<dim3(Bb * Hh * (Vv / 4)), 320, 0, stream>>>(
      qc, kc, vc, beta, on);
  // 6. convert Wo into dead vc slot
  cvt_w_kernel<<<dim3(8, 8, 1), 256, 0, stream>>>(Wo, Wo, Wo, wohi, wolo);
  // 7. RMSNorm -> split-bf16 `on`
  rmsnorm_kernel<<<dim3(Bb * Tt * Hh / 4), 256, 0, stream>>>(on, rmsw, onhi, onlo);
  // 8. output projection via MFMA (64x64 tiles)
  gemm1_mfma_kernel<<<dim3(BT / 64, HK / 64, 1), 256, 0, stream>>>(
      onhi, onlo, wohi, wolo, out);
}

// Round 26
// 180.266 us; speedup vs baseline: 1.0840x; 1.0840x over previous
//
#include <hip/hip_runtime.h>
#include <hip/hip_bf16.h>
#include <math.h>

// Dims (compile-time constants for this problem)
#define Bb 2
#define Tt 1024
#define Dd 512
#define Hh 8
#define Kk 64
#define Vv 64
#define BT (Bb*Tt)          // 2048
#define HK (Hh*Kk)          // 512

// hyperparams
#define B1c 0.9f
#define B2c 0.999f
#define LRc 1e-3f
#define SCALEc 0.125f       // 64^-0.5

typedef short s8v __attribute__((ext_vector_type(8)));   // 8 bf16 = 4 VGPR
typedef float f4v __attribute__((ext_vector_type(4)));   // MFMA acc

// ---------------------------------------------------------------------------
// bf16 split helpers (RNE)
// ---------------------------------------------------------------------------
__device__ __forceinline__ unsigned short f2bf(float x) {
  unsigned u = __float_as_uint(x);
  u += 0x7FFFu + ((u >> 16) & 1u);
  return (unsigned short)(u >> 16);
}
__device__ __forceinline__ float bf2f(unsigned short h) {
  return __uint_as_float((unsigned)h << 16);
}

// ---------------------------------------------------------------------------
// Cross-lane helpers: all-VALU butterfly stages
// ---------------------------------------------------------------------------
template <int CTRL>
__device__ __forceinline__ float dpp_add(float v) {
  int y = __builtin_amdgcn_update_dpp(0, __float_as_int(v), CTRL, 0xF, 0xF, true);
  return v + __int_as_float(y);
}

typedef unsigned uint2_t __attribute__((ext_vector_type(2)));

__device__ __forceinline__ float xor16_add(float x) {
#if __has_builtin(__builtin_amdgcn_permlane16_swap)
  uint2_t r = __builtin_amdgcn_permlane16_swap(__float_as_uint(x), __float_as_uint(x),
                                               false, false);
  return __uint_as_float(r.x) + __uint_as_float(r.y);
#else
  int y = __builtin_amdgcn_ds_swizzle(__float_as_int(x), 0x401F);
  return x + __int_as_float(y);
#endif
}

__device__ __forceinline__ float xor32_add(float x) {
#if __has_builtin(__builtin_amdgcn_permlane32_swap)
  uint2_t r = __builtin_amdgcn_permlane32_swap(__float_as_uint(x), __float_as_uint(x),
                                               false, false);
  return __uint_as_float(r.x) + __uint_as_float(r.y);
#else
  return x + __shfl_xor(x, 32, 64);
#endif
}

__device__ __forceinline__ float reduce16(float x) {
  x = dpp_add<0xB1>(x);
  x = dpp_add<0x4E>(x);
  x = dpp_add<0x141>(x);
  x = dpp_add<0x140>(x);
  return x;
}

__device__ __forceinline__ float reduce64(float x) {
  x = reduce16(x);
  x = xor16_add(x);
  x = xor32_add(x);
  return x;
}

// ---------------------------------------------------------------------------
// cvt_x: fp32 [M][512] -> hi/lo bf16 [M][512] (row-major)
// ---------------------------------------------------------------------------
__global__ __launch_bounds__(256) void cvt_x_kernel(
    const float* __restrict__ x, unsigned short* __restrict__ hi,
    unsigned short* __restrict__ lo) {
  const int i = (blockIdx.x * 256 + threadIdx.x) * 8;
  float4 a = *(const float4*)(x + i);
  float4 b = *(const float4*)(x + i + 4);
  const float v[8] = {a.x, a.y, a.z, a.w, b.x, b.y, b.z, b.w};
  union { unsigned short u[8]; uint4 q; } ph, pl;
#pragma unroll
  for (int j = 0; j < 8; ++j) {
    unsigned short h = f2bf(v[j]);
    ph.u[j] = h;
    pl.u[j] = f2bf(v[j] - bf2f(h));
  }
  *(uint4*)(hi + i) = ph.q;
  *(uint4*)(lo + i) = pl.q;
}

// ---------------------------------------------------------------------------
// cvt_w: W [512 k][512 n] fp32 -> hi/lo bf16 TRANSPOSED [n][k].
// ---------------------------------------------------------------------------
__global__ __launch_bounds__(256) void cvt_w_kernel(
    const float* __restrict__ W0, const float* __restrict__ W1,
    const float* __restrict__ W2,
    unsigned short* __restrict__ hib, unsigned short* __restrict__ lob) {
  __shared__ float Ts[64][65];
  const int z = blockIdx.z;
  const float* W = (z == 0) ? W0 : (z == 1) ? W1 : W2;
  unsigned short* hi = hib + (size_t)z * 512 * 512;
  unsigned short* lo = lob + (size_t)z * 512 * 512;
  const int tk = blockIdx.x * 64;
  const int tn = blockIdx.y * 64;
  const int r  = threadIdx.x >> 2;
  const int cg = threadIdx.x & 3;
#pragma unroll
  for (int j = 0; j < 4; ++j) {
    float4 v = *(const float4*)(W + (size_t)(tk + r) * 512 + tn + cg * 16 + j * 4);
    Ts[r][cg * 16 + j * 4 + 0] = v.x;
    Ts[r][cg * 16 + j * 4 + 1] = v.y;
    Ts[r][cg * 16 + j * 4 + 2] = v.z;
    Ts[r][cg * 16 + j * 4 + 3] = v.w;
  }
  __syncthreads();
  union { unsigned short u[16]; uint4 q[2]; } ph, pl;
#pragma unroll
  for (int j = 0; j < 16; ++j) {
    float v = Ts[cg * 16 + j][r];
    unsigned short h = f2bf(v);
    ph.u[j] = h;
    pl.u[j] = f2bf(v - bf2f(h));
  }
  const size_t ob = (size_t)(tn + r) * 512 + tk + cg * 16;
  *(uint4*)(hi + ob) = ph.q[0];
  *(uint4*)(hi + ob + 8) = ph.q[1];
  *(uint4*)(lo + ob) = pl.q[0];
  *(uint4*)(lo + ob + 8) = pl.q[1];
}

// ---------------------------------------------------------------------------
// split-bf16 MFMA GEMM — 64x64 tile (R16/R20 winner)
// ---------------------------------------------------------------------------
__device__ __forceinline__ void gemm_mfma_body(
    const unsigned short* __restrict__ Ahi, const unsigned short* __restrict__ Alo,
    const unsigned short* __restrict__ Bhi, const unsigned short* __restrict__ Blo,
    float* __restrict__ C) {
  __shared__ unsigned short Ah[64][40], Al[64][40], Bh[64][40], Bl[64][40];
  const int tid = threadIdx.x;
  const int bm = blockIdx.x * 64;
  const int bn = blockIdx.y * 64;
  const int srow = tid >> 2;
  const int skoff = (tid & 3) * 8;
  const int l = tid & 63, w = tid >> 6;
  const int arow = (l & 15) + 16 * w;
  const int koff = (l >> 4) * 8;

  const unsigned short* pAh = Ahi + (size_t)(bm + srow) * 512 + skoff;
  const unsigned short* pAl = Alo + (size_t)(bm + srow) * 512 + skoff;
  const unsigned short* pBh = Bhi + (size_t)(bn + srow) * 512 + skoff;
  const unsigned short* pBl = Blo + (size_t)(bn + srow) * 512 + skoff;

  f4v acc0 = {0.f, 0.f, 0.f, 0.f}, acc1 = acc0, acc2 = acc0, acc3 = acc0;

  uint4 rah = *(const uint4*)(pAh);
  uint4 ral = *(const uint4*)(pAl);
  uint4 rbh = *(const uint4*)(pBh);
  uint4 rbl = *(const uint4*)(pBl);

  for (int k0 = 0; k0 < 512; k0 += 32) {
    __syncthreads();
    *(uint4*)&Ah[srow][skoff] = rah;
    *(uint4*)&Al[srow][skoff] = ral;
    *(uint4*)&Bh[srow][skoff] = rbh;
    *(uint4*)&Bl[srow][skoff] = rbl;
    __syncthreads();
    if (k0 + 32 < 512) {
      rah = *(const uint4*)(pAh + k0 + 32);
      ral = *(const uint4*)(pAl + k0 + 32);
      rbh = *(const uint4*)(pBh + k0 + 32);
      rbl = *(const uint4*)(pBl + k0 + 32);
    }
    const s8v ah = *(const s8v*)&Ah[arow][koff];
    const s8v al = *(const s8v*)&Al[arow][koff];
#pragma unroll
    for (int c = 0; c < 4; ++c) {
      const s8v bh = *(const s8v*)&Bh[16 * c + (l & 15)][koff];
      const s8v bl = *(const s8v*)&Bl[16 * c + (l & 15)][koff];
      f4v* acc = (c == 0) ? &acc0 : (c == 1) ? &acc1 : (c == 2) ? &acc2 : &acc3;
      *acc = __builtin_amdgcn_mfma_f32_16x16x32_bf16(al, bh, *acc, 0, 0, 0);
      *acc = __builtin_amdgcn_mfma_f32_16x16x32_bf16(ah, bl, *acc, 0, 0, 0);
      *acc = __builtin_amdgcn_mfma_f32_16x16x32_bf16(ah, bh, *acc, 0, 0, 0);
    }
  }

  const int crow = bm + 16 * w + (l >> 4) * 4;
  const int ccol = bn + (l & 15);
#pragma unroll
  for (int i = 0; i < 4; ++i) {
    C[(size_t)(crow + i) * 512 + ccol + 0]  = acc0[i];
    C[(size_t)(crow + i) * 512 + ccol + 16] = acc1[i];
    C[(size_t)(crow + i) * 512 + ccol + 32] = acc2[i];
    C[(size_t)(crow + i) * 512 + ccol + 48] = acc3[i];
  }
}

__global__ __launch_bounds__(256) void gemm3_mfma_kernel(
    const unsigned short* __restrict__ xhi, const unsigned short* __restrict__ xlo,
    const unsigned short* __restrict__ whi, const unsigned short* __restrict__ wlo,
    float* __restrict__ qp, float* __restrict__ kp, float* __restrict__ vp) {
  const int z = blockIdx.z;
  float* Cp = (z == 0) ? qp : (z == 1) ? kp : vp;
  gemm_mfma_body(xhi, xlo, whi + (size_t)z * 512 * 512, wlo + (size_t)z * 512 * 512, Cp);
}

__global__ __launch_bounds__(256) void gemm1_mfma_kernel(
    const unsigned short* __restrict__ ahi, const unsigned short* __restrict__ alo,
    const unsigned short* __restrict__ whi, const unsigned short* __restrict__ wlo,
    float* __restrict__ C) {
  gemm_mfma_body(ahi, alo, whi, wlo, C);
}

// ---------------------------------------------------------------------------
// beta = sigmoid(x @ Wb) (float4-vectorized)
// ---------------------------------------------------------------------------
__global__ __launch_bounds__(256) void beta_kernel(const float* __restrict__ x,
                                                   const float* __restrict__ Wb,
                                                   float* __restrict__ beta) {
  int gid = blockIdx.x * blockDim.x + threadIdx.x;
  int bt = gid >> 3, h = gid & 7;
  const float4* xr = (const float4*)(x + (size_t)bt * Dd);
  float s = 0.f;
#pragma unroll 4
  for (int d4 = 0; d4 < Dd / 4; ++d4) {
    float4 xv = xr[d4];
    const float* wb = Wb + (d4 * 4) * Hh + h;
    s = fmaf(xv.x, wb[0 * Hh], s);
    s = fmaf(xv.y, wb[1 * Hh], s);
    s = fmaf(xv.z, wb[2 * Hh], s);
    s = fmaf(xv.w, wb[3 * Hh], s);
  }
  beta[gid] = 1.f / (1.f + expf(-s));
}

// ---------------------------------------------------------------------------
// causal depthwise conv(4) + SiLU (+ optional L2 norm + scale)
// ---------------------------------------------------------------------------
__global__ __launch_bounds__(256) void conv_kernel(
    const float* __restrict__ qp, const float* __restrict__ kp,
    const float* __restrict__ vp,
    const float* __restrict__ cwq, const float* __restrict__ cwk,
    const float* __restrict__ cwv,
    float* __restrict__ qc, float* __restrict__ kc, float* __restrict__ vc) {
  const int mode = blockIdx.z;
  const float* pre; const float* cw; float* post;
  if (mode == 0)      { pre = qp; cw = cwq; post = qc; }
  else if (mode == 1) { pre = kp; cw = cwk; post = kc; }
  else                { pre = vp; cw = cwv; post = vc; }

  const int idx = blockIdx.x * 4 + (threadIdx.x >> 6);
  const int lane = threadIdx.x & 63;
  const int b = idx >> 13;
  const int th = idx & 8191;
  const int t = th >> 3;
  const int h = th & 7;
  const int ch = h * 64 + lane;

  float y = 0.f;
#pragma unroll
  for (int i = 0; i < 4; ++i) {
    int tt = t + i - 3;
    if (tt >= 0)
      y += pre[((size_t)(b * Tt + tt)) * HK + ch] * cw[ch * 4 + i];
  }
  y = y / (1.f + expf(-y));
  if (mode < 2) {
    float ss = reduce64(y * y);
    y *= rsqrtf(ss + 1e-6f);
    if (mode == 0) y *= SCALEc;
  }
  post[((size_t)(b * Tt + t)) * HK + ch] = y;
}

// ---------------------------------------------------------------------------
// sequential IVON delta-rule scan — producer/consumer wave specialization
// (R24 winner, restored).
//  A-waves (0-3, one per column): S-chain only — kv read, scalar head,
//    ONE 6-stage pred-reduce, ds_write S. Minimal issue (R25 showed adding
//    issue to the producer to shorten its reduce is a net loss).
//  B-waves (4-7): all staging + per tile compute o for the PREVIOUS tile
//    from S values A wrote to LDS (32 independent reduce64 per column).
// Triple-buffered ks/qs/vb; double-buffered Sb; single barrier per tile.
// 2 waves/SIMD: B's issue fills A's chain-stall slots.
// ---------------------------------------------------------------------------
#define TC 32           // steps per LDS tile
#define NT (Tt / TC)    // 32 tiles

__global__ __launch_bounds__(512) void scan_kernel(
    const float* __restrict__ qc, const float* __restrict__ kc,
    const float* __restrict__ vc, const float* __restrict__ beta,
    float* __restrict__ o) {
  __shared__ float  ks[3][TC][64];     // 24576 B
  __shared__ float  qs[3][TC][64];     // 24576 B
  __shared__ float2 vb[3][TC][4];      //  3072 B
  __shared__ float  Sb[2][TC][4][64];  // 65536 B

  const int tid  = threadIdx.x;       // 0..511
  const int lane = tid & 63;
  const int wave = tid >> 6;          // 0..7
  const int bid  = blockIdx.x;        // 0..255
  const int vq   = bid >> 4;          // 0..15 (column quad)
  const int bh   = bid & 15;          // bid%8 == bh%8 -> XCD affinity
  const int b = bh >> 3, h = bh & 7;

  const size_t base2 = ((size_t)b * Tt) * HK + h * 64;
  const float* bp = beta + ((size_t)b * Tt) * Hh + h;

  // B staging thread mapping (tid2 = tid-256, 0..255)
  const int tid2 = tid - 256;
  const int sr = (tid2 & 255) >> 4;   // 0..15 (also +16)
  const int sg = tid2 & 15;
  const int vr = (tid2 & 255) >> 3;   // 0..31
  const int vcc = tid2 & 3;

  // ---- prologue: B stages tile 0 into buffer 0 ----
  if (wave >= 4) {
    float4 k0 = *(const float4*)(kc + base2 + (size_t)sr * HK + sg * 4);
    float4 q0 = *(const float4*)(qc + base2 + (size_t)sr * HK + sg * 4);
    float4 k1 = *(const float4*)(kc + base2 + (size_t)(sr + 16) * HK + sg * 4);
    float4 q1 = *(const float4*)(qc + base2 + (size_t)(sr + 16) * HK + sg * 4);
    *(float4*)&ks[0][sr][sg * 4] = k0;
    *(float4*)&qs[0][sr][sg * 4] = q0;
    *(float4*)&ks[0][sr + 16][sg * 4] = k1;
    *(float4*)&qs[0][sr + 16][sg * 4] = q1;
    if ((tid2 & 7) < 4) {
      float vv = vc[base2 + (size_t)vr * HK + vq * 4 + vcc];
      float lb = (0.1f * LRc) * bp[(size_t)vr * Hh];
      vb[0][vr][vcc] = make_float2(vv, lb);
    }
  }
  __syncthreads();

  float S = 0.f, G = 0.f, H = 0.f, r = 1.f;   // A state (junk in B waves)
  float pred = 0.f;

  int d = 0;                           // tile % 3
  for (int tile = 0; tile < NT; ++tile) {
    const int dn = (d + 1 == 3) ? 0 : d + 1;   // (tile+1)%3
    const int dm = (d == 0) ? 2 : d - 1;       // (tile-1)%3
    const int sb = tile & 1, sbp = sb ^ 1;
    const int t0 = tile * TC;
    const int more = (tile + 1 < NT);

    if (wave < 4) {
      // ================= A: S-chain producer =================
      const int w = wave;              // column within block
      // tile-top pred (tile 0: S=0 -> pred 0; handled naturally)
      pred = reduce64(ks[d][0][lane] * S);
#pragma unroll
      for (int s = 0; s < TC; ++s) {
        const float kv = ks[d][s][lane];
        const float2 vbc = vb[d][s][w];
        const float diff = pred - vbc.x;
        const float lrb = vbc.y;
        const float gr = kv * diff;
        G = fmaf(B1c, G, gr);
        H = fmaf(B2c, H, gr * gr);
        const float dd = fmaf(H, 0.001f, 1.0f);
        r = r * fmaf(-dd, r, 2.0f);          // carried Newton
        S = fmaf(-lrb, G * r, S);
        Sb[sb][s][w][lane] = S;              // hand off to consumer
        if (s + 1 < TC)
          pred = reduce64(ks[d][s + 1][lane] * S);
      }
    } else {
      // ================= B: staging + o-consumer =================
      // issue next tile's global loads first (latency hidden under work)
      float4 nk0, nq0, nk1, nq1; float nv = 0.f, nb = 0.f;
      if (more) {
        const int tn = t0 + TC;
        nk0 = *(const float4*)(kc + base2 + (size_t)(tn + sr) * HK + sg * 4);
        nq0 = *(const float4*)(qc + base2 + (size_t)(tn + sr) * HK + sg * 4);
        nk1 = *(const float4*)(kc + base2 + (size_t)(tn + sr + 16) * HK + sg * 4);
        nq1 = *(const float4*)(qc + base2 + (size_t)(tn + sr + 16) * HK + sg * 4);
        if ((tid2 & 7) < 4) {
          nv = vc[base2 + (size_t)(tn + vr) * HK + vq * 4 + vcc];
          nb = (0.1f * LRc) * bp[(size_t)(tn + vr) * Hh];
        }
      }
      // compute o for the PREVIOUS tile (S in Sb[sbp], q in qs[dm])
      if (tile > 0) {
        const int cb = wave - 4;             // column within block
        float* opc = o + base2 + vq * 4 + cb;
        const int tp0 = t0 - TC;
#pragma unroll
        for (int s = 0; s < TC; ++s) {
          const float qv = qs[dm][s][lane];
          const float Sv = Sb[sbp][s][cb][lane];
          const float po = reduce64(qv * Sv);
          opc[(size_t)(tp0 + s) * HK] = po;  // maskless: uniform across wave
        }
      }
      // write staged tile t+1 into buffer dn
      if (more) {
        *(float4*)&ks[dn][sr][sg * 4] = nk0;
        *(float4*)&qs[dn][sr][sg * 4] = nq0;
        *(float4*)&ks[dn][sr + 16][sg * 4] = nk1;
        *(float4*)&qs[dn][sr + 16][sg * 4] = nq1;
        if ((tid2 & 7) < 4) vb[dn][vr][vcc] = make_float2(nv, nb);
      }
    }
    __syncthreads();
    d = dn;
  }

  // ---- epilogue: B computes o for the last tile ----
  if (wave >= 4) {
    const int dlast = (NT - 1) % 3;
    const int sbl = (NT - 1) & 1;
    const int cb = wave - 4;
    float* opc = o + base2 + vq * 4 + cb;
    const int tp0 = (NT - 1) * TC;
#pragma unroll
    for (int s = 0; s < TC; ++s) {
      const float qv = qs[dlast][s][lane];
      const float Sv = Sb[sbl][s][cb][lane];
      const float po = reduce64(qv * Sv);
      opc[(size_t)(tp0 + s) * HK] = po;
    }
  }
}

// ---------------------------------------------------------------------------
// RMSNorm over V=64, writes bf16 hi/lo for the MFMA output projection
// ---------------------------------------------------------------------------
__global__ __launch_bounds__(256) void rmsnorm_kernel(
    const float* __restrict__ o, const float* __restrict__ rmsw,
    unsigned short* __restrict__ hi, unsigned short* __restrict__ lo) {
  const int idx = blockIdx.x * 4 + (threadIdx.x >> 6);
  const int lane = threadIdx.x & 63;
  const float* p = o + (size_t)idx * 64;
  float y = p[lane];
  float ss = reduce64(y * y);
  y = y * rsqrtf(ss * (1.f / 64.f) + 1e-5f) * rmsw[lane];
  unsigned short h = f2bf(y);
  hi[(size_t)idx * 64 + lane] = h;
  lo[(size_t)idx * 64 + lane] = f2bf(y - bf2f(h));
}

// ---------------------------------------------------------------------------
extern "C" void kernel_launch(void* const* d_in, const int* in_sizes, int n_in,
                              void* d_out, int out_size, void* d_ws, size_t ws_size,
                              hipStream_t stream) {
  const float* x    = (const float*)d_in[0];
  const float* Wq   = (const float*)d_in[1];
  const float* Wk   = (const float*)d_in[2];
  const float* Wv   = (const float*)d_in[3];
  const float* Wb   = (const float*)d_in[4];
  const float* cwq  = (const float*)d_in[5];
  const float* cwk  = (const float*)d_in[6];
  const float* cwv  = (const float*)d_in[7];
  const float* rmsw = (const float*)d_in[8];
  const float* Wo   = (const float*)d_in[9];
  float* out = (float*)d_out;
  float* ws  = (float*)d_ws;

  const size_t SZ = (size_t)BT * HK;   // 1,048,576 floats
  float* qp   = ws;            // pre-conv q / scan output `on`
  float* kp   = ws + 1 * SZ;   // pre-conv k; dead after conv -> onhi
  float* vp   = ws + 2 * SZ;   // pre-conv v; dead after conv -> onlo
  float* qc   = ws + 3 * SZ;   // conv q; hosts xhi/xlo BEFORE conv
  float* kc   = ws + 4 * SZ;   // conv k; hosts Wqkv hi/lo BEFORE conv
  float* vc   = ws + 5 * SZ;   // conv v; hosts Wo hi/lo AFTER scan
  float* beta = ws + 6 * SZ;   // 16384 floats
  float* on   = qp;

  unsigned short* xhi  = (unsigned short*)qc;
  unsigned short* xlo  = xhi + SZ;
  unsigned short* wh3  = (unsigned short*)kc;
  unsigned short* wl3  = wh3 + 3 * 512 * 512;
  unsigned short* wohi = (unsigned short*)vc;
  unsigned short* wolo = wohi + 512 * 512;
  unsigned short* onhi = (unsigned short*)kp;
  unsigned short* onlo = (unsigned short*)vp;

  // 1. convert x and Wq/Wk/Wv to split-bf16 (W transposed to [n][k])
  cvt_x_kernel<<<dim3(BT * Dd / (256 * 8)), 256, 0, stream>>>(x, xhi, xlo);
  cvt_w_kernel<<<dim3(8, 8, 3), 256, 0, stream>>>(Wq, Wk, Wv, wh3, wl3);
  // 2. projections via MFMA (64x64 tiles)
  gemm3_mfma_kernel<<<dim3(BT / 64, HK / 64, 3), 256, 0, stream>>>(
      xhi, xlo, wh3, wl3, qp, kp, vp);
  // 3. beta
  beta_kernel<<<dim3(BT * Hh / 256), 256, 0, stream>>>(x, Wb, beta);
  // 4. conv + silu + l2norm
  conv_kernel<<<dim3(Bb * Tt * Hh / 4, 1, 3), 256, 0, stream>>>(
      qp, kp, vp, cwq, cwk, cwv, qc, kc, vc);
  // 5. sequential scan: 256 blocks x 8 waves (4 producer + 4 consumer)
  scan_kernel<<<dim3(Bb * Hh * (Vv / 4)), 512, 0, stream>>>(
      qc, kc, vc, beta, on);
  // 6. convert Wo into dead vc slot
  cvt_w_kernel<<<dim3(8, 8, 1), 256, 0, stream>>>(Wo, Wo, Wo, wohi, wolo);
  // 7. RMSNorm -> split-bf16 `on`
  rmsnorm_kernel<<<dim3(Bb * Tt * Hh / 4), 256, 0, stream>>>(on, rmsw, onhi, onlo);
  // 8. output projection via MFMA (64x64 tiles)
  gemm1_mfma_kernel<<<dim3(BT / 64, HK / 64, 1), 256, 0, stream>>>(
      onhi, onlo, wohi, wolo, out);
}